// Round 3
// baseline (1163.548 us; speedup 1.0000x reference)
//
#include <hip/hip_runtime.h>
#include <hip/hip_fp16.h>
#include <stdint.h>

// GPTQ 4-bit fused dequant + f16 MFMA GEMM, two-pass, 8-phase pipelined.
// (Resubmission of Round-1 kernel: bench infra failed; audit found no race,
//  uniform barrier counts, no compile hazard.)
//
// Pass 1 (cvt_a): x f32 [8192][4096] -> xh f16, k-permuted per 8-chunk
//   ({0,4,1,5,2,6,3,7}) so GEMM A-staging is a straight 16B DMA copy.
// Pass 2 (gptq_gemm256): 256x256 tile, BK=64, 512 thr / 8 waves, double
//   buffered LDS (128 KiB), 4 phases per K-tile (T3+T4 schedule):
//     phase = { ds_read frags | stage-issue } s_barrier lgkm(0)
//             setprio(1) 16xMFMA setprio(0) s_barrier
//   Only ONE full drain (__syncthreads) per K-tile, so the A-tile DMA
//   (global_load_lds) issued in phases 0-1 stays in flight across the
//   intra-tile barriers (~3 phases of cover >> HBM latency).
//   B is reg-staged: qweight dword loads issued phase 0 (tile t+1),
//   dequant + swizzled ds_write in phase 3 (T14 issue-early/write-late).
//
// W[k][n] = s[g][n] * (w4 - (z4+1)), g = k/128.  Numerics identical to the
// verified kernel (same pkrtz conversion, dequant, MFMA shape, K order).

#define IN_F  4096
#define OUT_F 11008

typedef __attribute__((ext_vector_type(8))) _Float16 half8;  // 4 VGPRs
typedef __attribute__((ext_vector_type(4))) float f32x4;     // MFMA acc

__device__ __forceinline__ __half2 u2h2(uint32_t u) {
    union { uint32_t u; __half2 h; } c; c.u = u; return c.h;
}
__device__ __forceinline__ uint32_t h22u(__half2 h) {
    union { uint32_t u; __half2 h; } c; c.h = h; return c.u;
}
__device__ __forceinline__ uint32_t pkrtz(float lo, float hi) {
    union { __fp16 h[2]; uint32_t u; } c;
    *(decltype(__builtin_amdgcn_cvt_pkrtz(0.f,0.f))*)c.h =
        __builtin_amdgcn_cvt_pkrtz(lo, hi);
    return c.u;
}
__device__ __forceinline__ void async_copy16(const void* gsrc, void* ldst) {
    __builtin_amdgcn_global_load_lds(
        (const __attribute__((address_space(1))) uint32_t*)gsrc,
        (__attribute__((address_space(3))) uint32_t*)ldst,
        16, 0, 0);
}

// ---------------- Pass 1: f32 -> f16 with k-perm baked in ----------------
__global__ __launch_bounds__(256) void cvt_a(
    const float* __restrict__ x, uint4* __restrict__ xh)
{
    const size_t idx = (size_t)blockIdx.x * 256 + threadIdx.x;  // < 8192*512
    const float4* p = (const float4*)(x + idx * 8);
    const float4 lo = p[0], hi = p[1];
    uint4 w;
    w.x = pkrtz(lo.x, hi.x);   // k: 0,4
    w.y = pkrtz(lo.y, hi.y);   // k: 1,5
    w.z = pkrtz(lo.z, hi.z);   // k: 2,6
    w.w = pkrtz(lo.w, hi.w);   // k: 3,7
    xh[idx] = w;
}

// ---------------- Pass 2: 256x256 GEMM, 8-phase ----------------
// LDS (uint4 units): A0[0..2047] A1[2048..4095] B0[4096..6143] B1[6144..8191]
// tile row layout: [row][chunk], chunk = 16B = 8 f16 along k, slot = ch^(row&7).

#define READ_A4(DST, AC, I0, KS)                                         \
    _Pragma("unroll") for (int i_ = 0; i_ < 4; ++i_) {                   \
        const int m_ = wm + ((I0) + i_) * 16 + ln15;                     \
        DST[i_] = *(const half8*)&AC[m_ * 8 + (((KS) * 4 + quad) ^ swz)];\
    }
#define READ_B4(DST, BC, KS)                                             \
    _Pragma("unroll") for (int j_ = 0; j_ < 4; ++j_) {                   \
        const int n_ = wn + j_ * 16 + ln15;                              \
        DST[j_] = *(const half8*)&BC[n_ * 8 + (((KS) * 4 + quad) ^ swz)];\
    }
#define MFMA16(I0, AV, BV)                                               \
    _Pragma("unroll") for (int i_ = 0; i_ < 4; ++i_)                     \
    _Pragma("unroll") for (int j_ = 0; j_ < 4; ++j_)                     \
        acc[(I0) + i_][j_] = __builtin_amdgcn_mfma_f32_16x16x32_f16(     \
            AV[i_], BV[j_], acc[(I0) + i_][j_], 0, 0, 0);
#define PHASE_MFMA(I0, AV, BV)                                           \
    __builtin_amdgcn_sched_barrier(0);                                   \
    __builtin_amdgcn_s_barrier();                                        \
    asm volatile("s_waitcnt lgkmcnt(0)" ::: "memory");                   \
    __builtin_amdgcn_sched_barrier(0);                                   \
    __builtin_amdgcn_s_setprio(1);                                       \
    MFMA16(I0, AV, BV);                                                  \
    __builtin_amdgcn_s_setprio(0);                                       \
    __builtin_amdgcn_sched_barrier(0);

__global__ __launch_bounds__(512, 2) void gptq_gemm256(
    const uint4* __restrict__ xh,
    const int*   __restrict__ qweight,
    const float* __restrict__ scales,
    const int*   __restrict__ qzeros,
    float* __restrict__ out)
{
    extern __shared__ uint4 smem[];

    const int t    = threadIdx.x;
    const int lane = t & 63;
    const int wave = t >> 6;
    const int n0   = blockIdx.x * 256;   // x-fast => n-fast: A panel L2 reuse
    const int m0   = blockIdx.y * 256;

    const int wm   = (wave >> 2) * 128;  // 2 waves in M
    const int wn   = (wave & 3) * 64;    // 4 waves in N
    const int ln15 = lane & 15;
    const int quad = lane >> 4;
    const int swz  = ln15 & 7;           // (row&7) for all frag reads

    f32x4 acc[8][4];
#pragma unroll
    for (int i = 0; i < 8; ++i)
#pragma unroll
        for (int j = 0; j < 4; ++j)
            acc[i][j] = (f32x4){0.f, 0.f, 0.f, 0.f};

    // A DMA: per wave 4 issues of 64 lanes x 16B = 1KB each (32KB/block =
    // full 256x64 f16 tile).  LDS dest linear (wave-uniform base + lane*16);
    // global source carries the XOR swizzle (rule #21 / m173).
    const int arow_l = lane >> 3;                 // row-within-8 = m&7
    const int xch    = (lane & 7) ^ arow_l;       // pre-swizzled source chunk
    const char* asrc[4];
#pragma unroll
    for (int q = 0; q < 4; ++q) {
        const int m = wave * 32 + q * 8 + arow_l;
        asrc[q] = (const char*)xh + ((size_t)(m0 + m) * 512 + xch) * 16;
    }
    const int aslot = wave * 256;                 // uint4 slot of issue q=0

    // B staging: thread covers col c = t&255, qweight rows r = b_r0 + 2i
    const int b_c  = t & 255;
    const int b_r0 = t >> 8;                      // 0 or 1
    const int n_th = n0 + b_c;
    const int*   qw_base = qweight + n_th;
    const float* sc_base = scales + n_th;
    const int*   qz_base = qzeros + (n_th >> 3);
    const int    z_shift = (n_th & 7) * 4;

    // ================= prologue: stage tile 0 =================
    {
        uint32_t bw[4];
#pragma unroll
        for (int i = 0; i < 4; ++i)
            bw[i] = (uint32_t)qw_base[(size_t)(b_r0 + 2 * i) * OUT_F];
        const float    s  = sc_base[0];
        const uint32_t zw = (uint32_t)qz_base[0];
#pragma unroll
        for (int q = 0; q < 4; ++q) {
            async_copy16(asrc[q], smem + aslot + q * 64);
            asrc[q] += 128;
        }
        const __half2 s2  = u2h2(pkrtz(s, s));
        const float   bzf = (float)(((zw >> z_shift) & 0xFu) + 1025u);
        const __half2 bz2 = u2h2(pkrtz(bzf, bzf));
        uint4* Bb = smem + 4096;
#pragma unroll
        for (int i = 0; i < 4; ++i) {
            const int r = b_r0 + 2 * i;
            const uint32_t w = bw[i];
            uint32_t q0 = ( w        & 0x000F000Fu) | 0x64006400u;
            uint32_t q1 = ((w >>  4) & 0x000F000Fu) | 0x64006400u;
            uint32_t q2 = ((w >>  8) & 0x000F000Fu) | 0x64006400u;
            uint32_t q3 = ((w >> 12) & 0x000F000Fu) | 0x64006400u;
            uint4 o;
            o.x = h22u(__hmul2(__hsub2(u2h2(q0), bz2), s2));
            o.y = h22u(__hmul2(__hsub2(u2h2(q1), bz2), s2));
            o.z = h22u(__hmul2(__hsub2(u2h2(q2), bz2), s2));
            o.w = h22u(__hmul2(__hsub2(u2h2(q3), bz2), s2));
            Bb[b_c * 8 + (r ^ (b_c & 7))] = o;
        }
        __syncthreads();   // full drain: tile-0 A DMA + B writes complete
    }

    // ================= main loop: 4 phases per K-tile =================
    for (int tile = 0; tile < 64; ++tile) {
        const int  cur = tile & 1;
        const int  nxt = cur ^ 1;
        const bool pf  = (tile < 63);
        const uint4* Ac = smem + (cur ? 2048 : 0);
        const uint4* Bc = smem + 4096 + (cur ? 2048 : 0);
        uint4* An = smem + (nxt ? 2048 : 0);
        uint4* Bn = smem + 4096 + (nxt ? 2048 : 0);

        uint32_t nbw[4]; float ns = 0.f; uint32_t nzw = 0;

        // ---- phase 0: frags(ks0, i0..3 + b) | issue B loads + 2 A-DMA ----
        half8 a0[4], b0[4];
        READ_A4(a0, Ac, 0, 0);
        READ_B4(b0, Bc, 0);
        if (pf) {
            const int kq0 = (tile + 1) * 8;
#pragma unroll
            for (int i = 0; i < 4; ++i)
                nbw[i] = (uint32_t)qw_base[(size_t)(kq0 + b_r0 + 2 * i) * OUT_F];
            const int g = (tile + 1) >> 1;
            ns  = sc_base[(size_t)g * OUT_F];
            nzw = (uint32_t)qz_base[(size_t)g * (OUT_F / 8)];
            async_copy16(asrc[0], An + aslot);       asrc[0] += 128;
            async_copy16(asrc[1], An + aslot + 64);  asrc[1] += 128;
        }
        PHASE_MFMA(0, a0, b0);
        __builtin_amdgcn_s_barrier();

        // ---- phase 1: frags(ks0, i4..7) | issue 2 A-DMA ----
        half8 a1[4];
        READ_A4(a1, Ac, 4, 0);
        if (pf) {
            async_copy16(asrc[2], An + aslot + 128); asrc[2] += 128;
            async_copy16(asrc[3], An + aslot + 192); asrc[3] += 128;
        }
        PHASE_MFMA(4, a1, b0);
        __builtin_amdgcn_s_barrier();

        // ---- phase 2: frags(ks1, i0..3 + b) ----
        half8 a2[4], b1[4];
        READ_A4(a2, Ac, 0, 1);
        READ_B4(b1, Bc, 1);
        PHASE_MFMA(0, a2, b1);
        __builtin_amdgcn_s_barrier();

        // ---- phase 3: frags(ks1, i4..7) | dequant + ds_write B(t+1) ----
        half8 a3[4];
        READ_A4(a3, Ac, 4, 1);
        if (pf) {
            const __half2 s2  = u2h2(pkrtz(ns, ns));
            const float   bzf = (float)(((nzw >> z_shift) & 0xFu) + 1025u);
            const __half2 bz2 = u2h2(pkrtz(bzf, bzf));
#pragma unroll
            for (int i = 0; i < 4; ++i) {
                const int r = b_r0 + 2 * i;
                const uint32_t w = nbw[i];
                uint32_t q0 = ( w        & 0x000F000Fu) | 0x64006400u;
                uint32_t q1 = ((w >>  4) & 0x000F000Fu) | 0x64006400u;
                uint32_t q2 = ((w >>  8) & 0x000F000Fu) | 0x64006400u;
                uint32_t q3 = ((w >> 12) & 0x000F000Fu) | 0x64006400u;
                uint4 o;
                o.x = h22u(__hmul2(__hsub2(u2h2(q0), bz2), s2));
                o.y = h22u(__hmul2(__hsub2(u2h2(q1), bz2), s2));
                o.z = h22u(__hmul2(__hsub2(u2h2(q2), bz2), s2));
                o.w = h22u(__hmul2(__hsub2(u2h2(q3), bz2), s2));
                Bn[b_c * 8 + (r ^ (b_c & 7))] = o;
            }
        }
        PHASE_MFMA(4, a3, b1);
        // tile-end: full drain (vmcnt: A-DMA issued ph0/ph1 has ~3 phases of
        // cover; lgkm: B ds_writes visible to all waves next tile).
        __syncthreads();
    }

    // ---- epilogue: C/D layout col = lane&15, row = quad*4 + reg
#pragma unroll
    for (int i = 0; i < 8; ++i) {
#pragma unroll
        for (int j = 0; j < 4; ++j) {
            const int col  = n0 + wn + j * 16 + ln15;
            const int row0 = m0 + wm + i * 16 + quad * 4;
            float* p = out + (size_t)row0 * OUT_F + col;
#pragma unroll
            for (int r = 0; r < 4; ++r)
                p[(size_t)r * OUT_F] = acc[i][j][r];
        }
    }
}

// ---------------- Fallback: verified 128x128 single-pass kernel ----------------
__global__ __launch_bounds__(256, 4) void gptq_gemm(
    const float* __restrict__ x,
    const int*   __restrict__ qweight,
    const float* __restrict__ scales,
    const int*   __restrict__ qzeros,
    float* __restrict__ out)
{
    __shared__ uint4 As[128 * 8];
    __shared__ uint4 Bs[128 * 8];

    const int t    = threadIdx.x;
    const int lane = t & 63;
    const int wave = t >> 6;
    const int n0   = blockIdx.x * 128;
    const int m0   = blockIdx.y * 128;

    const int wm   = (wave >> 1) * 64;
    const int wn   = (wave & 1) * 64;
    const int ln15 = lane & 15;
    const int quad = lane >> 4;

    f32x4 acc[4][4];
#pragma unroll
    for (int i = 0; i < 4; ++i)
#pragma unroll
        for (int j = 0; j < 4; ++j)
            acc[i][j] = (f32x4){0.f, 0.f, 0.f, 0.f};

    const int a_m0 = t >> 3;
    const int a_c8 = t & 7;
    const float* x_base = x + (size_t)(m0 + a_m0) * IN_F + a_c8 * 8;

    const int b_c  = t & 127;
    const int b_r0 = t >> 7;
    const int n_th = n0 + b_c;
    const int*   qw_base = qweight + n_th;
    const float* sc_base = scales + n_th;
    const int*   qz_base = qzeros + (n_th >> 3);
    const int    z_shift = (n_th & 7) * 4;

    for (int k0 = 0; k0 < IN_F; k0 += 64) {
        float4 av[8];
#pragma unroll
        for (int i = 0; i < 4; ++i) {
            const float* p = x_base + (size_t)(32 * i) * IN_F + k0;
            av[2 * i]     = *(const float4*)p;
            av[2 * i + 1] = *(const float4*)(p + 4);
        }
        const int kq0 = k0 >> 3;
        uint32_t bw[4];
#pragma unroll
        for (int i = 0; i < 4; ++i)
            bw[i] = (uint32_t)qw_base[(size_t)(kq0 + b_r0 + 2 * i) * OUT_F];

        const int g = k0 >> 7;
        const float    s  = sc_base[(size_t)g * OUT_F];
        const uint32_t zw = (uint32_t)qz_base[(size_t)g * (OUT_F / 8)];
        const float    bzf = (float)(((zw >> z_shift) & 0xFu) + 1025u);
        const __half2  s2  = u2h2(pkrtz(s, s));
        const __half2  bz2 = u2h2(pkrtz(bzf, bzf));

        __syncthreads();

#pragma unroll
        for (int i = 0; i < 4; ++i) {
            const int m  = a_m0 + 32 * i;
            const int ch = a_c8 ^ (m & 7);
            const float4 lo = av[2 * i], hi = av[2 * i + 1];
            uint4 w;
            w.x = pkrtz(lo.x, hi.x);
            w.y = pkrtz(lo.y, hi.y);
            w.z = pkrtz(lo.z, hi.z);
            w.w = pkrtz(lo.w, hi.w);
            As[m * 8 + ch] = w;
        }
#pragma unroll
        for (int i = 0; i < 4; ++i) {
            const int r = b_r0 + 2 * i;
            const uint32_t w = bw[i];
            uint32_t q0 = ( w        & 0x000F000Fu) | 0x64006400u;
            uint32_t q1 = ((w >>  4) & 0x000F000Fu) | 0x64006400u;
            uint32_t q2 = ((w >>  8) & 0x000F000Fu) | 0x64006400u;
            uint32_t q3 = ((w >> 12) & 0x000F000Fu) | 0x64006400u;
            uint4 o;
            o.x = h22u(__hmul2(__hsub2(u2h2(q0), bz2), s2));
            o.y = h22u(__hmul2(__hsub2(u2h2(q1), bz2), s2));
            o.z = h22u(__hmul2(__hsub2(u2h2(q2), bz2), s2));
            o.w = h22u(__hmul2(__hsub2(u2h2(q3), bz2), s2));
            const int ch = r ^ (b_c & 7);
            Bs[b_c * 8 + ch] = o;
        }
        __syncthreads();

#pragma unroll
        for (int ks = 0; ks < 2; ++ks) {
            half8 af[4], bf[4];
#pragma unroll
            for (int i = 0; i < 4; ++i) {
                const int m  = wm + i * 16 + ln15;
                const int ch = (ks * 4 + quad) ^ (m & 7);
                af[i] = *(const half8*)&As[m * 8 + ch];
            }
#pragma unroll
            for (int j = 0; j < 4; ++j) {
                const int n  = wn + j * 16 + ln15;
                const int ch = (ks * 4 + quad) ^ (n & 7);
                bf[j] = *(const half8*)&Bs[n * 8 + ch];
            }
#pragma unroll
            for (int i = 0; i < 4; ++i)
#pragma unroll
                for (int j = 0; j < 4; ++j)
                    acc[i][j] = __builtin_amdgcn_mfma_f32_16x16x32_f16(
                        af[i], bf[j], acc[i][j], 0, 0, 0);
        }
    }

#pragma unroll
    for (int i = 0; i < 4; ++i) {
#pragma unroll
        for (int j = 0; j < 4; ++j) {
            const int col  = n0 + wn + j * 16 + ln15;
            const int row0 = m0 + wm + i * 16 + quad * 4;
            float* p = out + (size_t)row0 * OUT_F + col;
#pragma unroll
            for (int r = 0; r < 4; ++r)
                p[(size_t)r * OUT_F] = acc[i][j][r];
        }
    }
}

extern "C" void kernel_launch(void* const* d_in, const int* in_sizes, int n_in,
                              void* d_out, int out_size, void* d_ws, size_t ws_size,
                              hipStream_t stream) {
    const float* x       = (const float*)d_in[0];
    const int*   qweight = (const int*)d_in[1];
    const float* scales  = (const float*)d_in[2];
    const int*   qzeros  = (const int*)d_in[3];
    float* out = (float*)d_out;

    const size_t xh_bytes = (size_t)8192 * IN_F * 2;   // 64 MiB f16 copy of x
    if (d_ws != nullptr && ws_size >= xh_bytes) {
        static bool attr_done = false;
        if (!attr_done) {
            (void)hipFuncSetAttribute(
                reinterpret_cast<const void*>(gptq_gemm256),
                hipFuncAttributeMaxDynamicSharedMemorySize, 131072);
            attr_done = true;
        }
        uint4* xh = (uint4*)d_ws;
        cvt_a<<<(8192 * 512) / 256, 256, 0, stream>>>(x, xh);
        dim3 grid(OUT_F / 256, 8192 / 256);   // 43 x 32, n-fast
        gptq_gemm256<<<grid, 512, 131072, stream>>>(xh, qweight, scales, qzeros, out);
    } else {
        dim3 grid(OUT_F / 128, 8192 / 128);
        gptq_gemm<<<grid, 256, 0, stream>>>(x, qweight, scales, qzeros, out);
    }
}

// Round 4
// 1129.525 us; speedup vs baseline: 1.0301x; 1.0301x over previous
//
#include <hip/hip_runtime.h>
#include <hip/hip_fp16.h>
#include <stdint.h>

// GPTQ 4-bit fused dequant + f16 MFMA GEMM, two-pass, B-in-register version.
//
// Pass 1 (cvt_a): x f32 [8192][4096] -> xh f16, k-permuted per 8-chunk
//   ({0,4,1,5,2,6,3,7}) so GEMM A-staging is a straight 16B DMA copy.
// Pass 2 (gptq_gemm256): 256x256 tile, BK=64, 512 thr / 8 waves.
//   A: double-buffered LDS (64 KiB) via global_load_lds DMA (pre-swizzled
//      per-lane global source, linear LDS dest).
//   B: NO LDS. Each wave gathers its own 8 qweight dwords/tile and the
//      magic-number dequant produces MFMA B-fragments directly in registers:
//      lane l, frag j covers col n = wn + j*16 + (l&15), dword row
//      R = tile*8 + ks*4 + quad; nibble pairs (0,4)(1,5)(2,6)(3,7) match the
//      k-permutation baked into A.  This removes ~40% of LDS-pipe traffic and
//      all intra-tile barriers: ONE __syncthreads per K-tile, waves free-run,
//      so ds_read bursts of one wave overlap MFMA bursts of another.
//
// W[k][n] = s[g][n] * (w4 - (z4+1)), g = k/128.  Per-element numerics
// identical to the verified kernel (same pkrtz conversion, dequant, MFMA
// shape and K order).  Fallback to verified 128x128 kernel if ws too small.

#define IN_F  4096
#define OUT_F 11008
#define QZ_W  (OUT_F / 8)   // 1376

typedef __attribute__((ext_vector_type(8))) _Float16 half8;  // 4 VGPRs
typedef __attribute__((ext_vector_type(4))) float f32x4;     // MFMA acc

__device__ __forceinline__ __half2 u2h2(uint32_t u) {
    union { uint32_t u; __half2 h; } c; c.u = u; return c.h;
}
__device__ __forceinline__ uint32_t h22u(__half2 h) {
    union { uint32_t u; __half2 h; } c; c.h = h; return c.u;
}
__device__ __forceinline__ uint32_t pkrtz(float lo, float hi) {
    union { __fp16 h[2]; uint32_t u; } c;
    *(decltype(__builtin_amdgcn_cvt_pkrtz(0.f,0.f))*)c.h =
        __builtin_amdgcn_cvt_pkrtz(lo, hi);
    return c.u;
}
__device__ __forceinline__ void async_copy16(const void* gsrc, void* ldst) {
    __builtin_amdgcn_global_load_lds(
        (const __attribute__((address_space(1))) uint32_t*)gsrc,
        (__attribute__((address_space(3))) uint32_t*)ldst,
        16, 0, 0);
}
// dequant one qweight dword -> one 8-f16 B fragment (k-perm {0,4,1,5,2,6,3,7})
__device__ __forceinline__ half8 dq8(uint32_t w, __half2 bz2, __half2 s2) {
    uint32_t q0 = ( w        & 0x000F000Fu) | 0x64006400u;  // n0,n4
    uint32_t q1 = ((w >>  4) & 0x000F000Fu) | 0x64006400u;  // n1,n5
    uint32_t q2 = ((w >>  8) & 0x000F000Fu) | 0x64006400u;  // n2,n6
    uint32_t q3 = ((w >> 12) & 0x000F000Fu) | 0x64006400u;  // n3,n7
    union { half8 h; uint32_t u[4]; } f;
    f.u[0] = h22u(__hmul2(__hsub2(u2h2(q0), bz2), s2));
    f.u[1] = h22u(__hmul2(__hsub2(u2h2(q1), bz2), s2));
    f.u[2] = h22u(__hmul2(__hsub2(u2h2(q2), bz2), s2));
    f.u[3] = h22u(__hmul2(__hsub2(u2h2(q3), bz2), s2));
    return f.h;
}

// ---------------- Pass 1: f32 -> f16 with k-perm baked in ----------------
__global__ __launch_bounds__(256) void cvt_a(
    const float* __restrict__ x, uint4* __restrict__ xh)
{
    const size_t idx = (size_t)blockIdx.x * 256 + threadIdx.x;  // < 8192*512
    const float4* p = (const float4*)(x + idx * 8);
    const float4 lo = p[0], hi = p[1];
    uint4 w;
    w.x = pkrtz(lo.x, hi.x);   // k: 0,4
    w.y = pkrtz(lo.y, hi.y);   // k: 1,5
    w.z = pkrtz(lo.z, hi.z);   // k: 2,6
    w.w = pkrtz(lo.w, hi.w);   // k: 3,7
    xh[idx] = w;
}

// ---------------- Pass 2: 256x256 GEMM, B-in-register ----------------
// LDS (uint4 units): A0[0..2047] A1[2048..4095] — 64 KB total.
// A tile row layout: [row][chunk], chunk = 16B = 8 f16, slot = ch ^ (row&7).
__global__ __launch_bounds__(512, 2) void gptq_gemm256(
    const uint4* __restrict__ xh,
    const int*   __restrict__ qweight,
    const float* __restrict__ scales,
    const int*   __restrict__ qzeros,
    float* __restrict__ out)
{
    extern __shared__ uint4 smem[];

    const int t    = threadIdx.x;
    const int lane = t & 63;
    const int wave = t >> 6;
    const int n0   = blockIdx.x * 256;   // x-fast => n-fast: A panel L2 reuse
    const int m0   = blockIdx.y * 256;

    const int wm   = (wave >> 2) * 128;  // 2 waves in M
    const int wn   = (wave & 3) * 64;    // 4 waves in N
    const int ln15 = lane & 15;
    const int quad = lane >> 4;
    const int swz  = ln15 & 7;

    f32x4 acc[8][4];
#pragma unroll
    for (int i = 0; i < 8; ++i)
#pragma unroll
        for (int j = 0; j < 4; ++j)
            acc[i][j] = (f32x4){0.f, 0.f, 0.f, 0.f};

    // ---- A DMA: per wave 4 issues of 64 lanes x 16B (32KB/block = full
    // 256x64 tile).  LDS dest linear; global source pre-swizzled (rule #21).
    const int arow_l = lane >> 3;
    const int xch    = (lane & 7) ^ arow_l;
    const char* asrc[4];
#pragma unroll
    for (int q = 0; q < 4; ++q) {
        const int m = wave * 32 + q * 8 + arow_l;
        asrc[q] = (const char*)xh + ((size_t)(m0 + m) * 512 + xch) * 16;
    }
    const int aslot = wave * 256;

    // ---- B per-frag-column constants: frag j covers col nj = n0+wn+j*16+ln15,
    // this lane's dword rows are quad + 4*ks + 8*tile.
    const int* qwp[4];
    int sc_ix[4], qz_ix[4], zsh[4];
#pragma unroll
    for (int j = 0; j < 4; ++j) {
        const int nj = n0 + wn + j * 16 + ln15;
        qwp[j]   = qweight + (size_t)quad * OUT_F + nj;
        sc_ix[j] = nj;
        qz_ix[j] = nj >> 3;
        zsh[j]   = (nj & 7) * 4;
    }

    // ================= prologue: tile 0 =================
    uint32_t bw[2][4];
#pragma unroll
    for (int ks = 0; ks < 2; ++ks)
#pragma unroll
        for (int j = 0; j < 4; ++j)
            bw[ks][j] = (uint32_t)qwp[j][(size_t)(ks * 4) * OUT_F];

    __half2 s2[4], bz2[4];
#pragma unroll
    for (int j = 0; j < 4; ++j) {
        const float    s  = scales[sc_ix[j]];
        const uint32_t zw = (uint32_t)qzeros[qz_ix[j]];
        s2[j]  = u2h2(pkrtz(s, s));
        const float bzf = (float)(((zw >> zsh[j]) & 0xFu) + 1025u); // 1024+z+1
        bz2[j] = u2h2(pkrtz(bzf, bzf));
    }
#pragma unroll
    for (int q = 0; q < 4; ++q) {
        async_copy16(asrc[q], smem + aslot + q * 64);
        asrc[q] += 128;
    }
    __syncthreads();   // tile-0 A DMA complete

    // ================= main loop: ONE barrier per K-tile =================
    for (int tile = 0; tile < 64; ++tile) {
        const int  cur = tile & 1;
        const bool pf  = (tile < 63);
        const uint4* Ac = smem + (cur ? 2048 : 0);
        uint4* An = smem + (cur ? 0 : 2048);

        // ---- prefetch tile+1: A DMA + B dword gathers (latency under MFMA)
        uint32_t nbw[2][4];
        if (pf) {
#pragma unroll
            for (int q = 0; q < 4; ++q) {
                async_copy16(asrc[q], An + aslot + q * 64);
                asrc[q] += 128;
            }
            const size_t r0 = (size_t)(tile + 1) * 8;
#pragma unroll
            for (int ks = 0; ks < 2; ++ks)
#pragma unroll
                for (int j = 0; j < 4; ++j)
                    nbw[ks][j] = (uint32_t)qwp[j][(r0 + ks * 4) * OUT_F];
        }
        // group scalars change every 2 tiles; issue gathers early
        const bool newg = pf && (((tile + 1) & 1) == 0);
        float nsr[4]; uint32_t nzr[4];
        if (newg) {
            const size_t g1 = (size_t)(tile + 1) >> 1;
#pragma unroll
            for (int j = 0; j < 4; ++j) {
                nsr[j] = scales[g1 * OUT_F + sc_ix[j]];
                nzr[j] = (uint32_t)qzeros[g1 * QZ_W + qz_ix[j]];
            }
        }

        // ---- dequant this tile's B directly to fragments (registers)
        half8 bf[2][4];
#pragma unroll
        for (int ks = 0; ks < 2; ++ks)
#pragma unroll
            for (int j = 0; j < 4; ++j)
                bf[ks][j] = dq8(bw[ks][j], bz2[j], s2[j]);

        // ---- A-frag reads + MFMA (compiler interleaves with fine lgkmcnt)
#pragma unroll
        for (int ks = 0; ks < 2; ++ks) {
            half8 af[8];
#pragma unroll
            for (int i = 0; i < 8; ++i) {
                const int m = wm + i * 16 + ln15;
                af[i] = *(const half8*)&Ac[m * 8 + (((ks * 4 + quad)) ^ swz)];
            }
#pragma unroll
            for (int i = 0; i < 8; ++i)
#pragma unroll
                for (int j = 0; j < 4; ++j)
                    acc[i][j] = __builtin_amdgcn_mfma_f32_16x16x32_f16(
                        af[i], bf[ks][j], acc[i][j], 0, 0, 0);
        }

        // ---- roll prefetched state into place
        if (newg) {
#pragma unroll
            for (int j = 0; j < 4; ++j) {
                s2[j] = u2h2(pkrtz(nsr[j], nsr[j]));
                const float bzf = (float)(((nzr[j] >> zsh[j]) & 0xFu) + 1025u);
                bz2[j] = u2h2(pkrtz(bzf, bzf));
            }
        }
        if (pf) {
#pragma unroll
            for (int ks = 0; ks < 2; ++ks)
#pragma unroll
                for (int j = 0; j < 4; ++j)
                    bw[ks][j] = nbw[ks][j];
        }
        // ONE barrier: (a) this tile's A reads precede overwrite of Ac next
        // tile; (b) drains vmcnt(0) so An's DMA is complete before next reads.
        __syncthreads();
    }

    // ---- epilogue: C/D layout col = lane&15, row = quad*4 + reg
#pragma unroll
    for (int i = 0; i < 8; ++i) {
#pragma unroll
        for (int j = 0; j < 4; ++j) {
            const int col  = n0 + wn + j * 16 + ln15;
            const int row0 = m0 + wm + i * 16 + quad * 4;
            float* p = out + (size_t)row0 * OUT_F + col;
#pragma unroll
            for (int r = 0; r < 4; ++r)
                p[(size_t)r * OUT_F] = acc[i][j][r];
        }
    }
}

// ---------------- Fallback: verified 128x128 single-pass kernel ----------------
__global__ __launch_bounds__(256, 4) void gptq_gemm(
    const float* __restrict__ x,
    const int*   __restrict__ qweight,
    const float* __restrict__ scales,
    const int*   __restrict__ qzeros,
    float* __restrict__ out)
{
    __shared__ uint4 As[128 * 8];
    __shared__ uint4 Bs[128 * 8];

    const int t    = threadIdx.x;
    const int lane = t & 63;
    const int wave = t >> 6;
    const int n0   = blockIdx.x * 128;
    const int m0   = blockIdx.y * 128;

    const int wm   = (wave >> 1) * 64;
    const int wn   = (wave & 1) * 64;
    const int ln15 = lane & 15;
    const int quad = lane >> 4;

    f32x4 acc[4][4];
#pragma unroll
    for (int i = 0; i < 4; ++i)
#pragma unroll
        for (int j = 0; j < 4; ++j)
            acc[i][j] = (f32x4){0.f, 0.f, 0.f, 0.f};

    const int a_m0 = t >> 3;
    const int a_c8 = t & 7;
    const float* x_base = x + (size_t)(m0 + a_m0) * IN_F + a_c8 * 8;

    const int b_c  = t & 127;
    const int b_r0 = t >> 7;
    const int n_th = n0 + b_c;
    const int*   qw_base = qweight + n_th;
    const float* sc_base = scales + n_th;
    const int*   qz_base = qzeros + (n_th >> 3);
    const int    z_shift = (n_th & 7) * 4;

    for (int k0 = 0; k0 < IN_F; k0 += 64) {
        float4 av[8];
#pragma unroll
        for (int i = 0; i < 4; ++i) {
            const float* p = x_base + (size_t)(32 * i) * IN_F + k0;
            av[2 * i]     = *(const float4*)p;
            av[2 * i + 1] = *(const float4*)(p + 4);
        }
        const int kq0 = k0 >> 3;
        uint32_t bwv[4];
#pragma unroll
        for (int i = 0; i < 4; ++i)
            bwv[i] = (uint32_t)qw_base[(size_t)(kq0 + b_r0 + 2 * i) * OUT_F];

        const int g = k0 >> 7;
        const float    s  = sc_base[(size_t)g * OUT_F];
        const uint32_t zw = (uint32_t)qz_base[(size_t)g * QZ_W];
        const float    bzf = (float)(((zw >> z_shift) & 0xFu) + 1025u);
        const __half2  s2  = u2h2(pkrtz(s, s));
        const __half2  bz2 = u2h2(pkrtz(bzf, bzf));

        __syncthreads();

#pragma unroll
        for (int i = 0; i < 4; ++i) {
            const int m  = a_m0 + 32 * i;
            const int ch = a_c8 ^ (m & 7);
            const float4 lo = av[2 * i], hi = av[2 * i + 1];
            uint4 w;
            w.x = pkrtz(lo.x, hi.x);
            w.y = pkrtz(lo.y, hi.y);
            w.z = pkrtz(lo.z, hi.z);
            w.w = pkrtz(lo.w, hi.w);
            As[m * 8 + ch] = w;
        }
#pragma unroll
        for (int i = 0; i < 4; ++i) {
            const int r = b_r0 + 2 * i;
            half8 o = dq8(bwv[i], bz2, s2);
            const int ch = r ^ (b_c & 7);
            *(half8*)&Bs[b_c * 8 + ch] = o;
        }
        __syncthreads();

#pragma unroll
        for (int ks = 0; ks < 2; ++ks) {
            half8 af[4], bfv[4];
#pragma unroll
            for (int i = 0; i < 4; ++i) {
                const int m  = wm + i * 16 + ln15;
                const int ch = (ks * 4 + quad) ^ (m & 7);
                af[i] = *(const half8*)&As[m * 8 + ch];
            }
#pragma unroll
            for (int j = 0; j < 4; ++j) {
                const int n  = wn + j * 16 + ln15;
                const int ch = (ks * 4 + quad) ^ (n & 7);
                bfv[j] = *(const half8*)&Bs[n * 8 + ch];
            }
#pragma unroll
            for (int i = 0; i < 4; ++i)
#pragma unroll
                for (int j = 0; j < 4; ++j)
                    acc[i][j] = __builtin_amdgcn_mfma_f32_16x16x32_f16(
                        af[i], bfv[j], acc[i][j], 0, 0, 0);
        }
    }

#pragma unroll
    for (int i = 0; i < 4; ++i) {
#pragma unroll
        for (int j = 0; j < 4; ++j) {
            const int col  = n0 + wn + j * 16 + ln15;
            const int row0 = m0 + wm + i * 16 + quad * 4;
            float* p = out + (size_t)row0 * OUT_F + col;
#pragma unroll
            for (int r = 0; r < 4; ++r)
                p[(size_t)r * OUT_F] = acc[i][j][r];
        }
    }
}

extern "C" void kernel_launch(void* const* d_in, const int* in_sizes, int n_in,
                              void* d_out, int out_size, void* d_ws, size_t ws_size,
                              hipStream_t stream) {
    const float* x       = (const float*)d_in[0];
    const int*   qweight = (const int*)d_in[1];
    const float* scales  = (const float*)d_in[2];
    const int*   qzeros  = (const int*)d_in[3];
    float* out = (float*)d_out;

    const size_t xh_bytes = (size_t)8192 * IN_F * 2;   // 64 MiB f16 copy of x
    if (d_ws != nullptr && ws_size >= xh_bytes) {
        static bool attr_done = false;
        if (!attr_done) {
            (void)hipFuncSetAttribute(
                reinterpret_cast<const void*>(gptq_gemm256),
                hipFuncAttributeMaxDynamicSharedMemorySize, 65536);
            attr_done = true;
        }
        uint4* xh = (uint4*)d_ws;
        cvt_a<<<(8192 * 512) / 256, 256, 0, stream>>>(x, xh);
        dim3 grid(OUT_F / 256, 8192 / 256);   // 43 x 32, n-fast
        gptq_gemm256<<<grid, 512, 65536, stream>>>(xh, qweight, scales, qzeros, out);
    } else {
        dim3 grid(OUT_F / 128, 8192 / 128);
        gptq_gemm<<<grid, 256, 0, stream>>>(x, qweight, scales, qzeros, out);
    }
}